// Round 1
// baseline (540.982 us; speedup 1.0000x reference)
//
#include <hip/hip_runtime.h>
#include <hip/hip_bf16.h>

#define BDIM 1024
#define NH 16
#define HD 64
#define BB 4
#define SS 2048
#define MTOT (BB*SS)   // 8192

typedef __bf16 bf16x8 __attribute__((ext_vector_type(8)));
typedef float f32x4 __attribute__((ext_vector_type(4)));

__device__ __forceinline__ unsigned short f2b(float f){
    union { float f; unsigned u; } v; v.f = f;
    unsigned r = v.u + 0x7fffu + ((v.u >> 16) & 1u);
    return (unsigned short)(r >> 16);
}
__device__ __forceinline__ float b2f(unsigned short h){
    union { unsigned u; float f; } v; v.u = ((unsigned)h) << 16;
    return v.f;
}

// ---------------- fp32 -> bf16 convert ----------------
__global__ void convert_f32_bf16(const float* __restrict__ in,
                                 unsigned short* __restrict__ out, int n4){
    int i = blockIdx.x * blockDim.x + threadIdx.x;
    if (i < n4){
        float4 v = ((const float4*)in)[i];
        ushort4 o;
        o.x = f2b(v.x); o.y = f2b(v.y); o.z = f2b(v.z); o.w = f2b(v.w);
        ((ushort4*)out)[i] = o;
    }
}

// ---------------- shared GEMM mainloop: C = A(MxK) * B^T(NxK), K=1024 ----------------
// 128x128 tile, BK=64, 4 waves each computing 64x64.
__device__ __forceinline__ void gemm_mainloop(
    const unsigned short* __restrict__ A,
    const unsigned short* __restrict__ Bw,
    unsigned short* At, unsigned short* Bt,
    f32x4 acc[4][4], int m0, int n0)
{
    const int tid  = threadIdx.x;
    const int lane = tid & 63;
    const int wave = tid >> 6;
    const int wr = wave >> 1, wc = wave & 1;
    const int lh = lane >> 4, ll = lane & 15;
    const int K = 1024;

    for (int k0 = 0; k0 < K; k0 += 64){
        #pragma unroll
        for (int c = 0; c < 4; ++c){
            int ch  = tid + c*256;       // 0..1023 chunks of 16B
            int row = ch >> 3;           // 0..127
            int off = (ch & 7) * 8;      // element offset in BK
            uint4 va = *(const uint4*)(A  + (size_t)(m0+row)*K + k0 + off);
            *(uint4*)(At + row*72 + off) = va;
            uint4 vb = *(const uint4*)(Bw + (size_t)(n0+row)*K + k0 + off);
            *(uint4*)(Bt + row*72 + off) = vb;
        }
        __syncthreads();
        #pragma unroll
        for (int ks = 0; ks < 2; ++ks){
            bf16x8 af[4], bfr[4];
            #pragma unroll
            for (int i = 0; i < 4; ++i)
                af[i] = *(const bf16x8*)(At + (wr*64 + i*16 + ll)*72 + ks*32 + lh*8);
            #pragma unroll
            for (int j = 0; j < 4; ++j)
                bfr[j] = *(const bf16x8*)(Bt + (wc*64 + j*16 + ll)*72 + ks*32 + lh*8);
            #pragma unroll
            for (int i = 0; i < 4; ++i)
                #pragma unroll
                for (int j = 0; j < 4; ++j)
                    acc[i][j] = __builtin_amdgcn_mfma_f32_16x16x32_bf16(af[i], bfr[j], acc[i][j], 0, 0, 0);
        }
        __syncthreads();
    }
}

// QKV projection: writes bf16 into (b,h,s,d) layout. grid (8, 64, 3)
__global__ __launch_bounds__(256, 2) void gemm_qkv(
    const unsigned short* __restrict__ Xb,
    const unsigned short* __restrict__ Wq,
    const unsigned short* __restrict__ Wk,
    const unsigned short* __restrict__ Wv,
    unsigned short* __restrict__ Qt,
    unsigned short* __restrict__ Kt,
    unsigned short* __restrict__ Vt)
{
    __shared__ alignas(16) unsigned short At[128*72];
    __shared__ alignas(16) unsigned short Bt[128*72];
    const unsigned short* Bw = (blockIdx.z == 0) ? Wq : (blockIdx.z == 1 ? Wk : Wv);
    unsigned short*       C  = (blockIdx.z == 0) ? Qt : (blockIdx.z == 1 ? Kt : Vt);
    const int m0 = blockIdx.y * 128, n0 = blockIdx.x * 128;
    f32x4 acc[4][4] = {};
    gemm_mainloop(Xb, Bw, At, Bt, acc, m0, n0);

    const int lane = threadIdx.x & 63;
    const int wave = threadIdx.x >> 6;
    const int wr = wave >> 1, wc = wave & 1;
    const int lh = lane >> 4, ll = lane & 15;
    #pragma unroll
    for (int i = 0; i < 4; ++i)
        #pragma unroll
        for (int j = 0; j < 4; ++j)
            #pragma unroll
            for (int r = 0; r < 4; ++r){
                int m = m0 + wr*64 + i*16 + lh*4 + r;
                int n = n0 + wc*64 + j*16 + ll;
                int b = m >> 11, s = m & (SS-1);
                int h = n >> 6,  d = n & 63;
                C[(((size_t)(b*NH + h)*SS + s) << 6) + d] = f2b(acc[i][j][r]);
            }
}

// Output projection: fp32 out, row-major. grid (8, 64)
__global__ __launch_bounds__(256, 2) void gemm_out(
    const unsigned short* __restrict__ Ab,
    const unsigned short* __restrict__ Wo,
    float* __restrict__ Cout)
{
    __shared__ alignas(16) unsigned short At[128*72];
    __shared__ alignas(16) unsigned short Bt[128*72];
    const int m0 = blockIdx.y * 128, n0 = blockIdx.x * 128;
    f32x4 acc[4][4] = {};
    gemm_mainloop(Ab, Wo, At, Bt, acc, m0, n0);

    const int lane = threadIdx.x & 63;
    const int wave = threadIdx.x >> 6;
    const int wr = wave >> 1, wc = wave & 1;
    const int lh = lane >> 4, ll = lane & 15;
    #pragma unroll
    for (int i = 0; i < 4; ++i)
        #pragma unroll
        for (int j = 0; j < 4; ++j)
            #pragma unroll
            for (int r = 0; r < 4; ++r){
                int m = m0 + wr*64 + i*16 + lh*4 + r;
                int n = n0 + wc*64 + j*16 + ll;
                Cout[(size_t)m*BDIM + n] = acc[i][j][r];
            }
}

// ---------------- RoPE (in place, fp32 math), Q also scaled by 1/8 ----------------
// grid (16384, 2), block 256 = 8 rows x 32 lanes
__global__ void rope_kernel(unsigned short* __restrict__ Qt,
                            unsigned short* __restrict__ Kt){
    int row = blockIdx.x * 8 + (threadIdx.x >> 5);   // 0..B*H*S-1
    int d   = threadIdx.x & 31;
    unsigned short* base = (blockIdx.y == 0 ? Qt : Kt) + (size_t)row * HD;
    int s = row & (SS - 1);
    // inv_freq = 10000^(-d/32) = exp2(-log2(10000)/32 * d)
    float theta = (float)s * exp2f(-0.41524101186092029f * (float)d);
    float sn, c;
    sincosf(theta, &sn, &c);
    float x1 = b2f(base[d]), x2 = b2f(base[d + 32]);
    float y1 = x1 * c - x2 * sn;
    float y2 = x2 * c + x1 * sn;
    if (blockIdx.y == 0){ y1 *= 0.125f; y2 *= 0.125f; }   // fold 1/sqrt(HD) into Q
    base[d]      = f2b(y1);
    base[d + 32] = f2b(y2);
}

// ---------------- flash attention: grid (S/64, B*H), block 256 ----------------
__global__ __launch_bounds__(256, 2) void attn_kernel(
    const unsigned short* __restrict__ Qt,
    const unsigned short* __restrict__ Kt,
    const unsigned short* __restrict__ Vt,
    unsigned short* __restrict__ Obuf)
{
    __shared__ alignas(16) unsigned short Ksh[64*72];      // [key][d]
    __shared__ alignas(16) unsigned short Vsh[64*72];      // transposed [d][key]
    __shared__ alignas(16) unsigned short Psh[4][16*72];   // per wave [m][key]

    const int tid  = threadIdx.x;
    const int lane = tid & 63;
    const int wave = tid >> 6;
    const int lh = lane >> 4, ll = lane & 15;
    const int qt = blockIdx.x;
    const int bh = blockIdx.y;
    const int q0 = qt * 64;
    const unsigned short* Qh = Qt + (size_t)bh * SS * HD;
    const unsigned short* Kh = Kt + (size_t)bh * SS * HD;
    const unsigned short* Vh = Vt + (size_t)bh * SS * HD;

    // Q fragments: wave handles query rows q0 + wave*16 + (0..15)
    bf16x8 qf[2];
    {
        int qrow = q0 + wave*16 + ll;
        #pragma unroll
        for (int ks = 0; ks < 2; ++ks)
            qf[ks] = *(const bf16x8*)(Qh + (size_t)qrow*HD + ks*32 + lh*8);
    }

    f32x4 o[4] = {};
    float mi[4], li[4];
    #pragma unroll
    for (int r = 0; r < 4; ++r){ mi[r] = -1e30f; li[r] = 0.f; }

    for (int kt = 0; kt <= qt; ++kt){
        int t0 = kt * 64;
        __syncthreads();   // previous iter's LDS reads done before restage
        #pragma unroll
        for (int c = 0; c < 2; ++c){
            int ch  = tid + c*256;      // 0..511
            int key = ch >> 3;
            int off = (ch & 7) * 8;
            uint4 kv = *(const uint4*)(Kh + (size_t)(t0+key)*HD + off);
            *(uint4*)(Ksh + key*72 + off) = kv;
            unsigned short tmp[8];
            *(uint4*)tmp = *(const uint4*)(Vh + (size_t)(t0+key)*HD + off);
            #pragma unroll
            for (int j2 = 0; j2 < 8; ++j2)
                Vsh[(off + j2)*72 + key] = tmp[j2];
        }
        __syncthreads();

        // scores = Q K^T (Q pre-scaled by 1/8)
        f32x4 sc[4] = {};
        #pragma unroll
        for (int ks = 0; ks < 2; ++ks)
            #pragma unroll
            for (int j = 0; j < 4; ++j){
                bf16x8 bfr = *(const bf16x8*)(Ksh + (j*16 + ll)*72 + ks*32 + lh*8);
                sc[j] = __builtin_amdgcn_mfma_f32_16x16x32_bf16(qf[ks], bfr, sc[j], 0, 0, 0);
            }

        if (kt == qt){   // causal mask on diagonal tile (t0 == q0)
            #pragma unroll
            for (int j = 0; j < 4; ++j){
                int key = j*16 + ll;
                #pragma unroll
                for (int r = 0; r < 4; ++r){
                    int qrow = wave*16 + lh*4 + r;
                    if (key > qrow) sc[j][r] = -1e30f;
                }
            }
        }

        // online softmax
        float mnew[4], alpha[4];
        #pragma unroll
        for (int r = 0; r < 4; ++r){
            float m = fmaxf(fmaxf(sc[0][r], sc[1][r]), fmaxf(sc[2][r], sc[3][r]));
            #pragma unroll
            for (int x = 1; x < 16; x <<= 1)
                m = fmaxf(m, __shfl_xor(m, x));
            mnew[r]  = fmaxf(mi[r], m);
            alpha[r] = __expf(mi[r] - mnew[r]);
            mi[r]    = mnew[r];
        }
        #pragma unroll
        for (int j = 0; j < 4; ++j)
            #pragma unroll
            for (int r = 0; r < 4; ++r)
                sc[j][r] = __expf(sc[j][r] - mnew[r]);
        #pragma unroll
        for (int r = 0; r < 4; ++r){
            float sum = sc[0][r] + sc[1][r] + sc[2][r] + sc[3][r];
            #pragma unroll
            for (int x = 1; x < 16; x <<= 1)
                sum += __shfl_xor(sum, x);
            li[r] = li[r]*alpha[r] + sum;
        }
        #pragma unroll
        for (int t = 0; t < 4; ++t)
            #pragma unroll
            for (int r = 0; r < 4; ++r)
                o[t][r] *= alpha[r];

        // P -> LDS (C-layout -> A-layout round trip)
        #pragma unroll
        for (int j = 0; j < 4; ++j)
            #pragma unroll
            for (int r = 0; r < 4; ++r)
                Psh[wave][(lh*4 + r)*72 + j*16 + ll] = f2b(sc[j][r]);
        __syncthreads();

        // O += P V
        #pragma unroll
        for (int ks = 0; ks < 2; ++ks){
            bf16x8 pf = *(const bf16x8*)(&Psh[wave][ll*72 + ks*32 + lh*8]);
            #pragma unroll
            for (int t = 0; t < 4; ++t){
                bf16x8 vf = *(const bf16x8*)(Vsh + (t*16 + ll)*72 + ks*32 + lh*8);
                o[t] = __builtin_amdgcn_mfma_f32_16x16x32_bf16(pf, vf, o[t], 0, 0, 0);
            }
        }
    }

    // finalize: write (b, s, h*64+d) bf16
    int b = bh >> 4, h = bh & 15;
    #pragma unroll
    for (int r = 0; r < 4; ++r){
        float inv = 1.0f / li[r];
        int q = q0 + wave*16 + lh*4 + r;
        size_t rowbase = ((size_t)(b*SS + q))*BDIM + h*HD;
        #pragma unroll
        for (int t = 0; t < 4; ++t)
            Obuf[rowbase + t*16 + ll] = f2b(o[t][r] * inv);
    }
}

extern "C" void kernel_launch(void* const* d_in, const int* in_sizes, int n_in,
                              void* d_out, int out_size, void* d_ws, size_t ws_size,
                              hipStream_t stream) {
    const float* x  = (const float*)d_in[0];
    const float* Wq = (const float*)d_in[1];
    const float* Wk = (const float*)d_in[2];
    const float* Wv = (const float*)d_in[3];
    const float* Wo = (const float*)d_in[4];
    // d_in[5] = mask: pure tril causal, handled analytically.

    char* w = (char*)d_ws;
    unsigned short* xb  = (unsigned short*)(w);                    // 16 MB
    unsigned short* wqb = (unsigned short*)(w + (16u  << 20));     // 2 MB each
    unsigned short* wkb = (unsigned short*)(w + (18u  << 20));
    unsigned short* wvb = (unsigned short*)(w + (20u  << 20));
    unsigned short* wob = (unsigned short*)(w + (22u  << 20));
    unsigned short* Qt  = (unsigned short*)(w + (24u  << 20));     // 16 MB each
    unsigned short* Kt  = (unsigned short*)(w + (40u  << 20));
    unsigned short* Vt  = (unsigned short*)(w + (56u  << 20));
    unsigned short* Ob  = (unsigned short*)(w + (72u  << 20));     // ends at 88 MB

    convert_f32_bf16<<<8192, 256, 0, stream>>>(x,  xb,  2097152);
    convert_f32_bf16<<<1024, 256, 0, stream>>>(Wq, wqb, 262144);
    convert_f32_bf16<<<1024, 256, 0, stream>>>(Wk, wkb, 262144);
    convert_f32_bf16<<<1024, 256, 0, stream>>>(Wv, wvb, 262144);
    convert_f32_bf16<<<1024, 256, 0, stream>>>(Wo, wob, 262144);

    gemm_qkv<<<dim3(8, 64, 3), 256, 0, stream>>>(xb, wqb, wkb, wvb, Qt, Kt, Vt);
    rope_kernel<<<dim3(16384, 2), 256, 0, stream>>>(Qt, Kt);
    attn_kernel<<<dim3(SS/64, BB*NH), 256, 0, stream>>>(Qt, Kt, Vt, Ob);
    gemm_out<<<dim3(8, 64), 256, 0, stream>>>(Ob, wob, (float*)d_out);
}

// Round 2
// 458.437 us; speedup vs baseline: 1.1801x; 1.1801x over previous
//
#include <hip/hip_runtime.h>
#include <hip/hip_bf16.h>

#define BDIM 1024
#define NH 16
#define HD 64
#define BB 4
#define SS 2048
#define MTOT (BB*SS)   // 8192
#define NT (SS/64)     // 32 key tiles

typedef __bf16 bf16x8 __attribute__((ext_vector_type(8)));
typedef float f32x4 __attribute__((ext_vector_type(4)));

__device__ __forceinline__ unsigned short f2b(float f){
    union { float f; unsigned u; } v; v.f = f;
    unsigned r = v.u + 0x7fffu + ((v.u >> 16) & 1u);
    return (unsigned short)(r >> 16);
}
__device__ __forceinline__ float b2f(unsigned short h){
    union { unsigned u; float f; } v; v.u = ((unsigned)h) << 16;
    return v.f;
}

// ---------------- fp32 -> bf16 converts ----------------
__global__ void convert_f32_bf16(const float* __restrict__ in,
                                 unsigned short* __restrict__ out, int n4){
    int i = blockIdx.x * blockDim.x + threadIdx.x;
    if (i < n4){
        float4 v = ((const float4*)in)[i];
        ushort4 o;
        o.x = f2b(v.x); o.y = f2b(v.y); o.z = f2b(v.z); o.w = f2b(v.w);
        ((ushort4*)out)[i] = o;
    }
}

// all 4 weights in one launch: grid (1024, 4)
__global__ void convert_weights(const float* __restrict__ Wq, const float* __restrict__ Wk,
                                const float* __restrict__ Wv, const float* __restrict__ Wo,
                                unsigned short* __restrict__ oq, unsigned short* __restrict__ ok,
                                unsigned short* __restrict__ ov, unsigned short* __restrict__ oo){
    const float* in = (blockIdx.y == 0) ? Wq : (blockIdx.y == 1) ? Wk : (blockIdx.y == 2) ? Wv : Wo;
    unsigned short* out = (blockIdx.y == 0) ? oq : (blockIdx.y == 1) ? ok : (blockIdx.y == 2) ? ov : oo;
    int i = blockIdx.x * blockDim.x + threadIdx.x;
    float4 v = ((const float4*)in)[i];
    ushort4 o;
    o.x = f2b(v.x); o.y = f2b(v.y); o.z = f2b(v.z); o.w = f2b(v.w);
    ((ushort4*)out)[i] = o;
}

// ---------------- shared GEMM mainloop: C = A(MxK) * B^T(NxK), K=1024 ----------------
__device__ __forceinline__ void gemm_mainloop(
    const unsigned short* __restrict__ A,
    const unsigned short* __restrict__ Bw,
    unsigned short* At, unsigned short* Bt,
    f32x4 acc[4][4], int m0, int n0)
{
    const int tid  = threadIdx.x;
    const int lane = tid & 63;
    const int wave = tid >> 6;
    const int wr = wave >> 1, wc = wave & 1;
    const int lh = lane >> 4, ll = lane & 15;
    const int K = 1024;

    for (int k0 = 0; k0 < K; k0 += 64){
        #pragma unroll
        for (int c = 0; c < 4; ++c){
            int ch  = tid + c*256;
            int row = ch >> 3;
            int off = (ch & 7) * 8;
            uint4 va = *(const uint4*)(A  + (size_t)(m0+row)*K + k0 + off);
            *(uint4*)(At + row*72 + off) = va;
            uint4 vb = *(const uint4*)(Bw + (size_t)(n0+row)*K + k0 + off);
            *(uint4*)(Bt + row*72 + off) = vb;
        }
        __syncthreads();
        #pragma unroll
        for (int ks = 0; ks < 2; ++ks){
            bf16x8 af[4], bfr[4];
            #pragma unroll
            for (int i = 0; i < 4; ++i)
                af[i] = *(const bf16x8*)(At + (wr*64 + i*16 + ll)*72 + ks*32 + lh*8);
            #pragma unroll
            for (int j = 0; j < 4; ++j)
                bfr[j] = *(const bf16x8*)(Bt + (wc*64 + j*16 + ll)*72 + ks*32 + lh*8);
            #pragma unroll
            for (int i = 0; i < 4; ++i)
                #pragma unroll
                for (int j = 0; j < 4; ++j)
                    acc[i][j] = __builtin_amdgcn_mfma_f32_16x16x32_bf16(af[i], bfr[j], acc[i][j], 0, 0, 0);
        }
        __syncthreads();
    }
}

// QKV projection: writes bf16 into (b,h,s,d) layout. grid (8, 64, 3)
__global__ __launch_bounds__(256, 2) void gemm_qkv(
    const unsigned short* __restrict__ Xb,
    const unsigned short* __restrict__ Wq,
    const unsigned short* __restrict__ Wk,
    const unsigned short* __restrict__ Wv,
    unsigned short* __restrict__ Qt,
    unsigned short* __restrict__ Kt,
    unsigned short* __restrict__ Vt)
{
    __shared__ alignas(16) unsigned short At[128*72];
    __shared__ alignas(16) unsigned short Bt[128*72];
    const unsigned short* Bw = (blockIdx.z == 0) ? Wq : (blockIdx.z == 1 ? Wk : Wv);
    unsigned short*       C  = (blockIdx.z == 0) ? Qt : (blockIdx.z == 1 ? Kt : Vt);
    const int m0 = blockIdx.y * 128, n0 = blockIdx.x * 128;
    f32x4 acc[4][4] = {};
    gemm_mainloop(Xb, Bw, At, Bt, acc, m0, n0);

    const int lane = threadIdx.x & 63;
    const int wave = threadIdx.x >> 6;
    const int wr = wave >> 1, wc = wave & 1;
    const int lh = lane >> 4, ll = lane & 15;
    #pragma unroll
    for (int i = 0; i < 4; ++i)
        #pragma unroll
        for (int j = 0; j < 4; ++j)
            #pragma unroll
            for (int r = 0; r < 4; ++r){
                int m = m0 + wr*64 + i*16 + lh*4 + r;
                int n = n0 + wc*64 + j*16 + ll;
                int b = m >> 11, s = m & (SS-1);
                int h = n >> 6,  d = n & 63;
                C[(((size_t)(b*NH + h)*SS + s) << 6) + d] = f2b(acc[i][j][r]);
            }
}

// Output projection: fp32 out, row-major. grid (8, 64)
__global__ __launch_bounds__(256, 2) void gemm_out(
    const unsigned short* __restrict__ Ab,
    const unsigned short* __restrict__ Wo,
    float* __restrict__ Cout)
{
    __shared__ alignas(16) unsigned short At[128*72];
    __shared__ alignas(16) unsigned short Bt[128*72];
    const int m0 = blockIdx.y * 128, n0 = blockIdx.x * 128;
    f32x4 acc[4][4] = {};
    gemm_mainloop(Ab, Wo, At, Bt, acc, m0, n0);

    const int lane = threadIdx.x & 63;
    const int wave = threadIdx.x >> 6;
    const int wr = wave >> 1, wc = wave & 1;
    const int lh = lane >> 4, ll = lane & 15;
    #pragma unroll
    for (int i = 0; i < 4; ++i)
        #pragma unroll
        for (int j = 0; j < 4; ++j)
            #pragma unroll
            for (int r = 0; r < 4; ++r){
                int m = m0 + wr*64 + i*16 + lh*4 + r;
                int n = n0 + wc*64 + j*16 + ll;
                Cout[(size_t)m*BDIM + n] = acc[i][j][r];
            }
}

// ---------------- RoPE (in place, fp32 math), Q also scaled by 1/8 ----------------
__global__ void rope_kernel(unsigned short* __restrict__ Qt,
                            unsigned short* __restrict__ Kt){
    int row = blockIdx.x * 8 + (threadIdx.x >> 5);
    int d   = threadIdx.x & 31;
    unsigned short* base = (blockIdx.y == 0 ? Qt : Kt) + (size_t)row * HD;
    int s = row & (SS - 1);
    float theta = (float)s * exp2f(-0.41524101186092029f * (float)d);
    float sn, c;
    sincosf(theta, &sn, &c);
    float x1 = b2f(base[d]), x2 = b2f(base[d + 32]);
    float y1 = x1 * c - x2 * sn;
    float y2 = x2 * c + x1 * sn;
    if (blockIdx.y == 0){ y1 *= 0.125f; y2 *= 0.125f; }
    base[d]      = f2b(y1);
    base[d + 32] = f2b(y2);
}

// ---------------- V transpose: (bh, s, d) -> (bh, d, s). grid (32, 64) ----------------
__global__ void transpose_v(const unsigned short* __restrict__ Vt,
                            unsigned short* __restrict__ VTt){
    __shared__ alignas(16) unsigned short T[64*72];
    const int tid = threadIdx.x;
    const int s0  = blockIdx.x * 64;
    const int bh  = blockIdx.y;
    const unsigned short* src = Vt  + (size_t)bh * SS * HD;
    unsigned short*       dst = VTt + (size_t)bh * HD * SS;
    #pragma unroll
    for (int c = 0; c < 2; ++c){
        int ch  = tid + c*256;
        int s   = ch >> 3;
        int off = (ch & 7) * 8;
        *(uint4*)(T + s*72 + off) = *(const uint4*)(src + (size_t)(s0+s)*HD + off);
    }
    __syncthreads();
    int d  = tid >> 2;
    int sb = (tid & 3) * 16;
    unsigned short tmp[16];
    #pragma unroll
    for (int j = 0; j < 16; ++j)
        tmp[j] = T[(sb + j)*72 + d];
    *(uint4*)(dst + (size_t)d*SS + s0 + sb)     = *(uint4*)(tmp);
    *(uint4*)(dst + (size_t)d*SS + s0 + sb + 8) = *(uint4*)(tmp + 8);
}

// ---------------- attention tile computation (one 16-row Q strip vs 64 keys) ----------
__device__ __forceinline__ void attn_tile(
    const bf16x8 qf[2], bool diag, int wave, int lh, int ll,
    const unsigned short* Ksh, const unsigned short* Vsh, unsigned short* Prow,
    float mi[4], float li[4], f32x4 o[4])
{
    f32x4 sc[4] = {};
    #pragma unroll
    for (int ks = 0; ks < 2; ++ks)
        #pragma unroll
        for (int j = 0; j < 4; ++j){
            bf16x8 bfr = *(const bf16x8*)(Ksh + (j*16 + ll)*72 + ks*32 + lh*8);
            sc[j] = __builtin_amdgcn_mfma_f32_16x16x32_bf16(qf[ks], bfr, sc[j], 0, 0, 0);
        }
    if (diag){
        #pragma unroll
        for (int j = 0; j < 4; ++j){
            int key = j*16 + ll;
            #pragma unroll
            for (int r = 0; r < 4; ++r){
                int qrow = wave*16 + lh*4 + r;
                if (key > qrow) sc[j][r] = -1e30f;
            }
        }
    }
    float mnew[4], alpha[4];
    #pragma unroll
    for (int r = 0; r < 4; ++r){
        float m = fmaxf(fmaxf(sc[0][r], sc[1][r]), fmaxf(sc[2][r], sc[3][r]));
        #pragma unroll
        for (int x = 1; x < 16; x <<= 1)
            m = fmaxf(m, __shfl_xor(m, x));
        mnew[r]  = fmaxf(mi[r], m);
        alpha[r] = __expf(mi[r] - mnew[r]);
        mi[r]    = mnew[r];
    }
    #pragma unroll
    for (int j = 0; j < 4; ++j)
        #pragma unroll
        for (int r = 0; r < 4; ++r)
            sc[j][r] = __expf(sc[j][r] - mnew[r]);
    #pragma unroll
    for (int r = 0; r < 4; ++r){
        float sum = sc[0][r] + sc[1][r] + sc[2][r] + sc[3][r];
        #pragma unroll
        for (int x = 1; x < 16; x <<= 1)
            sum += __shfl_xor(sum, x);
        li[r] = li[r]*alpha[r] + sum;
    }
    #pragma unroll
    for (int t = 0; t < 4; ++t)
        #pragma unroll
        for (int r = 0; r < 4; ++r)
            o[t][r] *= alpha[r];
    // P -> per-wave LDS (C-layout -> A-layout); same-wave DS ops are in-order,
    // no barrier needed
    #pragma unroll
    for (int j = 0; j < 4; ++j)
        #pragma unroll
        for (int r = 0; r < 4; ++r)
            Prow[(lh*4 + r)*72 + j*16 + ll] = f2b(sc[j][r]);
    #pragma unroll
    for (int ks = 0; ks < 2; ++ks){
        bf16x8 pf = *(const bf16x8*)(Prow + ll*72 + ks*32 + lh*8);
        #pragma unroll
        for (int t = 0; t < 4; ++t){
            bf16x8 vf = *(const bf16x8*)(Vsh + (t*16 + ll)*72 + ks*32 + lh*8);
            o[t] = __builtin_amdgcn_mfma_f32_16x16x32_bf16(pf, vf, o[t], 0, 0, 0);
        }
    }
}

// ---------------- flash attention, paired Q tiles: grid (16, 64), block 256 ----------
// Block bx handles query tiles qtA=bx and qtB=31-bx: exactly 33 tile-computations
// per block -> perfectly balanced; 1024 blocks x 4/CU = fully co-resident.
__global__ __launch_bounds__(256, 4) void attn_kernel(
    const unsigned short* __restrict__ Qt,
    const unsigned short* __restrict__ Kt,
    const unsigned short* __restrict__ VTt,
    unsigned short* __restrict__ Obuf)
{
    __shared__ alignas(16) unsigned short Ksh[64*72];       // [key][d]
    __shared__ alignas(16) unsigned short Vsh[64*72];       // [d][key] (from VT)
    __shared__ alignas(16) unsigned short PshA[4][16*72];
    __shared__ alignas(16) unsigned short PshB[4][16*72];

    const int tid  = threadIdx.x;
    const int lane = tid & 63;
    const int wave = tid >> 6;
    const int lh = lane >> 4, ll = lane & 15;
    const int qtA = blockIdx.x;          // 0..15
    const int qtB = NT - 1 - blockIdx.x; // 31..16
    const int bh  = blockIdx.y;
    const unsigned short* Qh  = Qt  + (size_t)bh * SS * HD;
    const unsigned short* Kh  = Kt  + (size_t)bh * SS * HD;
    const unsigned short* VTh = VTt + (size_t)bh * HD * SS;

    bf16x8 qfA[2], qfB[2];
    {
        int qrA = qtA*64 + wave*16 + ll;
        int qrB = qtB*64 + wave*16 + ll;
        #pragma unroll
        for (int ks = 0; ks < 2; ++ks){
            qfA[ks] = *(const bf16x8*)(Qh + (size_t)qrA*HD + ks*32 + lh*8);
            qfB[ks] = *(const bf16x8*)(Qh + (size_t)qrB*HD + ks*32 + lh*8);
        }
    }

    f32x4 oA[4] = {}, oB[4] = {};
    float miA[4], liA[4], miB[4], liB[4];
    #pragma unroll
    for (int r = 0; r < 4; ++r){ miA[r] = miB[r] = -1e30f; liA[r] = liB[r] = 0.f; }

    for (int kt = 0; kt <= qtB; ++kt){
        int t0 = kt * 64;
        __syncthreads();
        #pragma unroll
        for (int c = 0; c < 2; ++c){
            int ch  = tid + c*256;
            int row = ch >> 3;
            int off = (ch & 7) * 8;
            *(uint4*)(Ksh + row*72 + off) = *(const uint4*)(Kh  + (size_t)(t0+row)*HD + off);
            *(uint4*)(Vsh + row*72 + off) = *(const uint4*)(VTh + (size_t)row*SS + t0 + off);
        }
        __syncthreads();

        attn_tile(qfB, kt == qtB, wave, lh, ll, Ksh, Vsh, PshB[wave], miB, liB, oB);
        if (kt <= qtA)
            attn_tile(qfA, kt == qtA, wave, lh, ll, Ksh, Vsh, PshA[wave], miA, liA, oA);
    }

    int b = bh >> 4, h = bh & 15;
    #pragma unroll
    for (int r = 0; r < 4; ++r){
        float invA = 1.0f / liA[r];
        float invB = 1.0f / liB[r];
        int qA = qtA*64 + wave*16 + lh*4 + r;
        int qB = qtB*64 + wave*16 + lh*4 + r;
        size_t rbA = ((size_t)(b*SS + qA))*BDIM + h*HD;
        size_t rbB = ((size_t)(b*SS + qB))*BDIM + h*HD;
        #pragma unroll
        for (int t = 0; t < 4; ++t){
            Obuf[rbA + t*16 + ll] = f2b(oA[t][r] * invA);
            Obuf[rbB + t*16 + ll] = f2b(oB[t][r] * invB);
        }
    }
}

extern "C" void kernel_launch(void* const* d_in, const int* in_sizes, int n_in,
                              void* d_out, int out_size, void* d_ws, size_t ws_size,
                              hipStream_t stream) {
    const float* x  = (const float*)d_in[0];
    const float* Wq = (const float*)d_in[1];
    const float* Wk = (const float*)d_in[2];
    const float* Wv = (const float*)d_in[3];
    const float* Wo = (const float*)d_in[4];
    // d_in[5] = mask: pure tril causal, handled analytically.

    char* w = (char*)d_ws;
    unsigned short* xb  = (unsigned short*)(w);                    // 16 MB
    unsigned short* wqb = (unsigned short*)(w + (16u  << 20));     // 2 MB each
    unsigned short* wkb = (unsigned short*)(w + (18u  << 20));
    unsigned short* wvb = (unsigned short*)(w + (20u  << 20));
    unsigned short* wob = (unsigned short*)(w + (22u  << 20));
    unsigned short* Qt  = (unsigned short*)(w + (24u  << 20));     // 16 MB each
    unsigned short* Kt  = (unsigned short*)(w + (40u  << 20));
    unsigned short* Vt  = (unsigned short*)(w + (56u  << 20));
    unsigned short* Ob  = (unsigned short*)(w + (72u  << 20));
    unsigned short* VTt = (unsigned short*)(w + (88u  << 20));     // ends at 104 MB

    convert_f32_bf16<<<8192, 256, 0, stream>>>(x, xb, 2097152);
    convert_weights<<<dim3(1024, 4), 256, 0, stream>>>(Wq, Wk, Wv, Wo, wqb, wkb, wvb, wob);

    gemm_qkv<<<dim3(8, 64, 3), 256, 0, stream>>>(xb, wqb, wkb, wvb, Qt, Kt, Vt);
    rope_kernel<<<dim3(16384, 2), 256, 0, stream>>>(Qt, Kt);
    transpose_v<<<dim3(32, 64), 256, 0, stream>>>(Vt, VTt);
    attn_kernel<<<dim3(16, 64), 256, 0, stream>>>(Qt, Kt, VTt, Ob);
    gemm_out<<<dim3(8, 64), 256, 0, stream>>>(Ob, wob, (float*)d_out);
}